// Round 13
// baseline (289.032 us; speedup 1.0000x reference)
//
#include <hip/hip_runtime.h>

#define NR_FULL 150000
#define NR_USER 100000
#define NR_ITEM 50000
#define NR_TOT  300000
#define NUSR    100000
#define NR_X    150000                 // unified x-table rows (user+item)
#define DIM     64

#define BIN_ROWS  512
#define BIN_SHIFT 9
#define NBIN ((NR_TOT + BIN_ROWS - 1) / BIN_ROWS)   // 586

#define PART_E 8192
#define PART_T 512

#define SORT_T   512
#define SORT_CAP 12288                 // in-place fallback tier only

typedef __attribute__((ext_vector_type(4))) float f32x4;

// ---------- 0) fused prep: bf16 table build + coarse bin histogram ----------
__device__ __forceinline__ unsigned short f2bf(float f) {
    unsigned b = __float_as_uint(f);
    return (unsigned short)((b + 0x7fffu + ((b >> 16) & 1u)) >> 16);   // RNE
}

__global__ void prep_kernel(const float* __restrict__ ue, const float* __restrict__ ie,
                            unsigned short* __restrict__ tbl,
                            const int* __restrict__ fr, int nf,
                            const int* __restrict__ ur, int nu,
                            const int* __restrict__ ir, int ni,
                            int* __restrict__ bincnt) {
    __shared__ int s_h[NBIN];
    for (int b = threadIdx.x; b < NBIN; b += blockDim.x) s_h[b] = 0;
    __syncthreads();

    int t = blockIdx.x * blockDim.x + threadIdx.x;
    int stride = gridDim.x * blockDim.x;

    // task A: bf16 table
    const int nq = NR_X * (DIM / 4);                     // 2.4M chunks
    for (int q = t; q < nq; q += stride) {
        int u  = q >> 4;
        int d4 = q & 15;
        const float* src = ((u < NUSR) ? ue + (size_t)u * DIM
                                       : ie + (size_t)(u - NUSR) * DIM) + d4 * 4;
        f32x4 f = *(const f32x4*)src;
        ushort4 h;
        h.x = f2bf(f.x); h.y = f2bf(f.y); h.z = f2bf(f.z); h.w = f2bf(f.w);
        ((ushort4*)tbl)[q] = h;
    }

    // task B: bin histogram (LDS pre-aggregated)
    int nvec = nf >> 2;
    for (int i = t; i < nvec; i += stride) {
        int4 r4 = ((const int4*)fr)[i];
        atomicAdd(&s_h[r4.x >> BIN_SHIFT], 1);
        atomicAdd(&s_h[r4.y >> BIN_SHIFT], 1);
        atomicAdd(&s_h[r4.z >> BIN_SHIFT], 1);
        atomicAdd(&s_h[r4.w >> BIN_SHIFT], 1);
    }
    for (int i = (nvec << 2) + t; i < nf; i += stride)
        atomicAdd(&s_h[fr[i] >> BIN_SHIFT], 1);

    nvec = nu >> 2;
    for (int i = t; i < nvec; i += stride) {
        int4 r4 = ((const int4*)ur)[i];
        atomicAdd(&s_h[(r4.x + NR_FULL) >> BIN_SHIFT], 1);
        atomicAdd(&s_h[(r4.y + NR_FULL) >> BIN_SHIFT], 1);
        atomicAdd(&s_h[(r4.z + NR_FULL) >> BIN_SHIFT], 1);
        atomicAdd(&s_h[(r4.w + NR_FULL) >> BIN_SHIFT], 1);
    }
    for (int i = (nvec << 2) + t; i < nu; i += stride)
        atomicAdd(&s_h[(ur[i] + NR_FULL) >> BIN_SHIFT], 1);

    nvec = ni >> 2;
    for (int i = t; i < nvec; i += stride) {
        int4 r4 = ((const int4*)ir)[i];
        atomicAdd(&s_h[(r4.x + NR_FULL + NR_USER) >> BIN_SHIFT], 1);
        atomicAdd(&s_h[(r4.y + NR_FULL + NR_USER) >> BIN_SHIFT], 1);
        atomicAdd(&s_h[(r4.z + NR_FULL + NR_USER) >> BIN_SHIFT], 1);
        atomicAdd(&s_h[(r4.w + NR_FULL + NR_USER) >> BIN_SHIFT], 1);
    }
    for (int i = (nvec << 2) + t; i < ni; i += stride)
        atomicAdd(&s_h[(ir[i] + NR_FULL + NR_USER) >> BIN_SHIFT], 1);

    __syncthreads();
    for (int b = threadIdx.x; b < NBIN; b += blockDim.x) {
        int c = s_h[b];
        if (c) atomicAdd(&bincnt[b], c);
    }
}

// ---------- 1-alt) hist only (fp32 fallback tier) ----------
__global__ void hist_all(const int* __restrict__ fr, int nf,
                         const int* __restrict__ ur, int nu,
                         const int* __restrict__ ir, int ni,
                         int* __restrict__ bincnt) {
    __shared__ int s_h[NBIN];
    for (int b = threadIdx.x; b < NBIN; b += blockDim.x) s_h[b] = 0;
    __syncthreads();
    int t = blockIdx.x * blockDim.x + threadIdx.x;
    int stride = gridDim.x * blockDim.x;
    int nvec = nf >> 2;
    for (int i = t; i < nvec; i += stride) {
        int4 r4 = ((const int4*)fr)[i];
        atomicAdd(&s_h[r4.x >> BIN_SHIFT], 1);
        atomicAdd(&s_h[r4.y >> BIN_SHIFT], 1);
        atomicAdd(&s_h[r4.z >> BIN_SHIFT], 1);
        atomicAdd(&s_h[r4.w >> BIN_SHIFT], 1);
    }
    for (int i = (nvec << 2) + t; i < nf; i += stride)
        atomicAdd(&s_h[fr[i] >> BIN_SHIFT], 1);
    nvec = nu >> 2;
    for (int i = t; i < nvec; i += stride) {
        int4 r4 = ((const int4*)ur)[i];
        atomicAdd(&s_h[(r4.x + NR_FULL) >> BIN_SHIFT], 1);
        atomicAdd(&s_h[(r4.y + NR_FULL) >> BIN_SHIFT], 1);
        atomicAdd(&s_h[(r4.z + NR_FULL) >> BIN_SHIFT], 1);
        atomicAdd(&s_h[(r4.w + NR_FULL) >> BIN_SHIFT], 1);
    }
    for (int i = (nvec << 2) + t; i < nu; i += stride)
        atomicAdd(&s_h[(ur[i] + NR_FULL) >> BIN_SHIFT], 1);
    nvec = ni >> 2;
    for (int i = t; i < nvec; i += stride) {
        int4 r4 = ((const int4*)ir)[i];
        atomicAdd(&s_h[(r4.x + NR_FULL + NR_USER) >> BIN_SHIFT], 1);
        atomicAdd(&s_h[(r4.y + NR_FULL + NR_USER) >> BIN_SHIFT], 1);
        atomicAdd(&s_h[(r4.z + NR_FULL + NR_USER) >> BIN_SHIFT], 1);
        atomicAdd(&s_h[(r4.w + NR_FULL + NR_USER) >> BIN_SHIFT], 1);
    }
    for (int i = (nvec << 2) + t; i < ni; i += stride)
        atomicAdd(&s_h[(ir[i] + NR_FULL + NR_USER) >> BIN_SHIFT], 1);
    __syncthreads();
    for (int b = threadIdx.x; b < NBIN; b += blockDim.x) {
        int c = s_h[b];
        if (c) atomicAdd(&bincnt[b], c);
    }
}

// ---------- 2) scan bins -> binoff (NBIN+1) + gcursor ----------
__global__ void bin_scan(const int* __restrict__ bincnt, int* __restrict__ binoff,
                         int* __restrict__ gcursor, int nnz_tot) {
    __shared__ int s[NBIN];
    int t = threadIdx.x;
    if (t < NBIN) s[t] = bincnt[t];
    __syncthreads();
    for (int off = 1; off < NBIN; off <<= 1) {
        int a = 0;
        if (t < NBIN && t >= off) a = s[t - off];
        __syncthreads();
        if (t < NBIN) s[t] += a;
        __syncthreads();
    }
    if (t < NBIN) {
        int excl = (t == 0) ? 0 : s[t - 1];
        binoff[t] = excl;
        gcursor[t] = excl;
    }
    if (t == 0) binoff[NBIN] = nnz_tot;
}

// ---------- 3) block-local counting sort -> bin-grouped pairs ----------
// pair: low32 = val bits; high32 = (rlocal<<18) | ucol (unified x index)
__global__ __launch_bounds__(PART_T) void partition_kernel(
    const int* __restrict__ fr, const int* __restrict__ fc, const float* __restrict__ fv, int nf,
    const int* __restrict__ ur, const int* __restrict__ uc, const float* __restrict__ uv, int nu,
    const int* __restrict__ ir, const int* __restrict__ ic, const float* __restrict__ iv, int ni,
    int* __restrict__ gcursor, long long* __restrict__ pairs) {
    __shared__ long long s_stage[PART_E];        // 64 KB
    __shared__ int s_cnt[NBIN];
    __shared__ int s_start[NBIN + 1];
    __shared__ int s_cur[NBIN];
    __shared__ int s_gbase[NBIN];

    const int t = threadIdx.x;
    const int ntot = nf + nu + ni;
    const int base = blockIdx.x * PART_E;
    const int nE = min(PART_E, ntot - base);

    for (int b = t; b < NBIN; b += PART_T) s_cnt[b] = 0;
    __syncthreads();

    for (int k = 0; k < PART_E / PART_T; ++k) {
        int j = k * PART_T + t;
        if (j < nE) {
            int i = base + j;
            int g;
            if (i < nf)            g = fr[i];
            else if (i < nf + nu)  g = ur[i - nf] + NR_FULL;
            else                   g = ir[i - nf - nu] + NR_FULL + NR_USER;
            atomicAdd(&s_cnt[g >> BIN_SHIFT], 1);
        }
    }
    __syncthreads();

    for (int off = 1; off < NBIN; off <<= 1) {
        int i0 = t, i1 = t + PART_T;
        int a0 = (i0 < NBIN && i0 >= off) ? s_cnt[i0 - off] : 0;
        int a1 = (i1 < NBIN && i1 >= off) ? s_cnt[i1 - off] : 0;
        __syncthreads();
        if (i0 < NBIN) s_cnt[i0] += a0;
        if (i1 < NBIN) s_cnt[i1] += a1;
        __syncthreads();
    }
    for (int b = t; b < NBIN; b += PART_T) {
        int st = (b == 0) ? 0 : s_cnt[b - 1];
        s_start[b] = st;
        s_cur[b]   = st;
    }
    if (t == 0) s_start[NBIN] = s_cnt[NBIN - 1];
    __syncthreads();

    for (int b = t; b < NBIN; b += PART_T) {
        int cnt = s_start[b + 1] - s_start[b];
        s_gbase[b] = cnt ? atomicAdd(&gcursor[b], cnt) : 0;
    }

    for (int k = 0; k < PART_E / PART_T; ++k) {
        int j = k * PART_T + t;
        if (j < nE) {
            int i = base + j;
            int g, u; float v;
            if (i < nf)           { g = fr[i];                          u = fc[i];        v = fv[i]; }
            else if (i < nf + nu) { int q = i - nf;      g = ur[q] + NR_FULL;            u = uc[q];        v = uv[q]; }
            else                  { int q = i - nf - nu; g = ir[q] + NR_FULL + NR_USER;  u = ic[q] + NUSR; v = iv[q]; }
            int bin = g >> BIN_SHIFT;
            int rl  = g & (BIN_ROWS - 1);
            int lpos = atomicAdd(&s_cur[bin], 1);
            unsigned hi = ((unsigned)rl << 18) | (unsigned)u;
            s_stage[lpos] = ((long long)hi << 32) | (long long)__float_as_uint(v);
        }
    }
    __syncthreads();

    for (int j = t; j < nE; j += PART_T) {
        int lo = 0, hi2 = NBIN;
        while (hi2 - lo > 1) {
            int mid = (lo + hi2) >> 1;
            if (s_start[mid] <= j) lo = mid; else hi2 = mid;
        }
        pairs[s_gbase[lo] + (j - s_start[lo])] = s_stage[j];
    }
}

// ---------- 3b-v2) within-bin row sort: direct L2-window scatter ----------
// One block per bin. No LDS stage, no capacity limit: the 58KB write window
// lives in ONE block -> one XCD L2; scattered 8B writes dirty-merge in L2 and
// each line writes back once (round-4's amplification only occurs when the
// scatter footprint spans XCDs). LDS = 4KB counters -> all 586 blocks
// co-resident. Shuffle-based wave scan replaces 18-barrier Hillis-Steele.
__global__ __launch_bounds__(SORT_T) void sort_bins_v2(
    const int* __restrict__ binoff, const long long* __restrict__ pairs,
    long long* __restrict__ pairs2, int* __restrict__ rowptr, int nnz_tot) {
    __shared__ int s_cnt[BIN_ROWS];
    __shared__ int s_cur[BIN_ROWS];
    __shared__ int s_wsum[SORT_T / 64];

    const int t   = threadIdx.x;
    const int bin = blockIdx.x;
    const int beg = binoff[bin], end = binoff[bin + 1];
    const int nE  = end - beg;

    s_cnt[t] = 0;
    __syncthreads();

    // pass 1: histogram local rows (hi 4B of each pair)
    const unsigned* hi32 = (const unsigned*)(pairs + beg) + 1;   // stride 2
    for (int j = t; j < nE; j += SORT_T)
        atomicAdd(&s_cnt[hi32[2 * j] >> 18], 1);
    __syncthreads();

    // inclusive scan of 512 via wave shuffles + 8 wave sums
    const int lane = t & 63, wid = t >> 6;
    int cnt0 = s_cnt[t];
    int x = cnt0;
    #pragma unroll
    for (int off = 1; off < 64; off <<= 1) {
        int y = __shfl_up(x, off);
        if (lane >= off) x += y;
    }
    if (lane == 63) s_wsum[wid] = x;
    __syncthreads();
    if (t == 0) {
        int run = 0;
        #pragma unroll
        for (int w = 0; w < SORT_T / 64; ++w) { int c = s_wsum[w]; s_wsum[w] = run; run += c; }
    }
    __syncthreads();
    int excl = x + s_wsum[wid] - cnt0;

    s_cur[t] = excl;
    int g = bin * BIN_ROWS + t;
    if (g < NR_TOT) rowptr[g] = beg + excl;
    if (bin == 0 && t == 0) rowptr[NR_TOT] = nnz_tot;
    __syncthreads();

    // pass 2: direct scatter into the bin's window of pairs2
    for (int j = t; j < nE; j += SORT_T) {
        long long pe = pairs[beg + j];
        int rl = (int)((unsigned)((unsigned long long)pe >> 32) >> 18);
        int pos = atomicAdd(&s_cur[rl], 1);
        pairs2[beg + pos] = pe;
    }
}

// ---------- 3b-inplace) fallback when ws lacks pairs2 ----------
__global__ __launch_bounds__(SORT_T) void sort_bins(
    const int* __restrict__ binoff, long long* __restrict__ pairs,
    int* __restrict__ rowptr, int nnz_tot) {
    __shared__ long long s_stage[SORT_CAP];      // 96 KB
    __shared__ int s_cnt[BIN_ROWS];
    __shared__ int s_start[BIN_ROWS];
    __shared__ int s_cur[BIN_ROWS];

    const int t   = threadIdx.x;
    const int bin = blockIdx.x;
    const int beg = binoff[bin], end = binoff[bin + 1];
    const int nE  = end - beg;
    const int nS  = nE < SORT_CAP ? nE : SORT_CAP;

    s_cnt[t] = 0;
    __syncthreads();
    for (int j = t; j < nE; j += SORT_T) {
        unsigned hi = (unsigned)((unsigned long long)pairs[beg + j] >> 32);
        atomicAdd(&s_cnt[hi >> 18], 1);
    }
    __syncthreads();
    for (int off = 1; off < BIN_ROWS; off <<= 1) {
        int a = (t >= off) ? s_cnt[t - off] : 0;
        __syncthreads();
        s_cnt[t] += a;
        __syncthreads();
    }
    int excl = (t == 0) ? 0 : s_cnt[t - 1];
    s_start[t] = excl;
    s_cur[t]   = excl;
    int g = bin * BIN_ROWS + t;
    if (g < NR_TOT) rowptr[g] = beg + excl;
    if (bin == 0 && t == 0) rowptr[NR_TOT] = nnz_tot;
    __syncthreads();
    for (int j = t; j < nE; j += SORT_T) {
        long long pe = pairs[beg + j];
        unsigned hi = (unsigned)((unsigned long long)pe >> 32);
        int pos = atomicAdd(&s_cur[hi >> 18], 1);
        if (pos < SORT_CAP) s_stage[pos] = pe;
    }
    __syncthreads();
    for (int j = t; j < nS; j += SORT_T)
        pairs[beg + j] = s_stage[j];
}

// ---------- 4) SpMM (bf16 gathers): one wave per row, 8x8 structure ----------
// 8 x 8-lane groups; lane loads 16B (8 lanes = 128B row); group owns 2
// contiguous edges -> 16 edges in flight per wave-iter, 4 VMEM instr/iter.
__global__ void spmm_bf16(const int* __restrict__ rowptr,
                          const long long* __restrict__ pairs,
                          const unsigned short* __restrict__ tbl,
                          float* __restrict__ out) {
    const int lane = threadIdx.x & 63;
    const int sub  = lane & 7;           // 16B slot within 128B bf16 row
    const int grp  = lane >> 3;          // edge group 0..7
    int wave  = (blockIdx.x * blockDim.x + threadIdx.x) >> 6;
    int nwave = (gridDim.x * blockDim.x) >> 6;
    for (int g = wave; g < NR_TOT; g += nwave) {
        int beg = rowptr[g], end = rowptr[g + 1];
        float acc[8] = {0.f, 0.f, 0.f, 0.f, 0.f, 0.f, 0.f, 0.f};
        if (beg < end) {
            int elast = end - 1;
            for (int e0 = beg + grp * 2; e0 < end; e0 += 16) {
                float v[2];
                uint4 h[2];
#pragma unroll
                for (int i = 0; i < 2; ++i) {
                    int ee = e0 + i;
                    bool ok = ee < end;
                    ee = ok ? ee : elast;
                    long long p = __builtin_nontemporal_load(&pairs[ee]);
                    v[i] = ok ? __uint_as_float((unsigned)p) : 0.f;
                    unsigned u = ((unsigned)((unsigned long long)p >> 32)) & 0x3FFFF;
                    h[i] = ((const uint4*)(tbl + (size_t)u * DIM))[sub];
                }
#pragma unroll
                for (int i = 0; i < 2; ++i) {
                    acc[0] = fmaf(v[i], __uint_as_float(h[i].x << 16),         acc[0]);
                    acc[1] = fmaf(v[i], __uint_as_float(h[i].x & 0xffff0000u), acc[1]);
                    acc[2] = fmaf(v[i], __uint_as_float(h[i].y << 16),         acc[2]);
                    acc[3] = fmaf(v[i], __uint_as_float(h[i].y & 0xffff0000u), acc[3]);
                    acc[4] = fmaf(v[i], __uint_as_float(h[i].z << 16),         acc[4]);
                    acc[5] = fmaf(v[i], __uint_as_float(h[i].z & 0xffff0000u), acc[5]);
                    acc[6] = fmaf(v[i], __uint_as_float(h[i].w << 16),         acc[6]);
                    acc[7] = fmaf(v[i], __uint_as_float(h[i].w & 0xffff0000u), acc[7]);
                }
            }
#pragma unroll
            for (int k = 0; k < 8; ++k) {
                acc[k] += __shfl_xor(acc[k], 8);
                acc[k] += __shfl_xor(acc[k], 16);
                acc[k] += __shfl_xor(acc[k], 32);
            }
        }
        if (grp == 0) {
            f32x4 lo = {acc[0], acc[1], acc[2], acc[3]};
            f32x4 hi = {acc[4], acc[5], acc[6], acc[7]};
            f32x4* o = (f32x4*)(out + (size_t)g * DIM) + sub * 2;
            __builtin_nontemporal_store(lo, o);
            __builtin_nontemporal_store(hi, o + 1);
        }
    }
}

// ---------- 4-alt) fp32 rowreg SpMM (used if ws lacks bf16 table) ----------
__global__ void spmm_rowreg(const int* __restrict__ rowptr,
                            const long long* __restrict__ pairs,
                            const float* __restrict__ user_emb,
                            const float* __restrict__ item_emb,
                            float* __restrict__ out) {
    const int lane = threadIdx.x & 63;
    const int sub  = lane & 15;
    const int grp  = lane >> 4;
    int wave  = (blockIdx.x * blockDim.x + threadIdx.x) >> 6;
    int nwave = (gridDim.x * blockDim.x) >> 6;
    for (int g = wave; g < NR_TOT; g += nwave) {
        int beg = rowptr[g], end = rowptr[g + 1];
        f32x4 acc = {0.f, 0.f, 0.f, 0.f};
        if (beg < end) {
            int elast = end - 1;
            for (int e = beg + grp; e < end; e += 8) {
                long long p0 = __builtin_nontemporal_load(&pairs[e]);
                int e1 = e + 4; bool ok1 = e1 <= elast; e1 = ok1 ? e1 : elast;
                long long p1 = __builtin_nontemporal_load(&pairs[e1]);
                float v0 = __uint_as_float((unsigned)p0);
                float v1 = ok1 ? __uint_as_float((unsigned)p1) : 0.f;
                unsigned u0 = ((unsigned)((unsigned long long)p0 >> 32)) & 0x3FFFF;
                unsigned u1 = ((unsigned)((unsigned long long)p1 >> 32)) & 0x3FFFF;
                const float* x0 = (u0 < NUSR) ? user_emb + (size_t)u0 * DIM
                                              : item_emb + (size_t)(u0 - NUSR) * DIM;
                const float* x1 = (u1 < NUSR) ? user_emb + (size_t)u1 * DIM
                                              : item_emb + (size_t)(u1 - NUSR) * DIM;
                f32x4 a = ((const f32x4*)x0)[sub];
                f32x4 b = ((const f32x4*)x1)[sub];
                acc.x = fmaf(v0, a.x, acc.x); acc.y = fmaf(v0, a.y, acc.y);
                acc.z = fmaf(v0, a.z, acc.z); acc.w = fmaf(v0, a.w, acc.w);
                acc.x = fmaf(v1, b.x, acc.x); acc.y = fmaf(v1, b.y, acc.y);
                acc.z = fmaf(v1, b.z, acc.z); acc.w = fmaf(v1, b.w, acc.w);
            }
            acc.x += __shfl_xor(acc.x, 16); acc.y += __shfl_xor(acc.y, 16);
            acc.z += __shfl_xor(acc.z, 16); acc.w += __shfl_xor(acc.w, 16);
            acc.x += __shfl_xor(acc.x, 32); acc.y += __shfl_xor(acc.y, 32);
            acc.z += __shfl_xor(acc.z, 32); acc.w += __shfl_xor(acc.w, 32);
        }
        if (grp == 0)
            __builtin_nontemporal_store(acc, (f32x4*)(out + (size_t)g * DIM) + sub);
    }
}

// ---------------- last-resort fallback (round-1 atomic scatter) ----------------
__global__ void spmm_scatter(const int* __restrict__ rows,
                             const int* __restrict__ cols,
                             const float* __restrict__ vals,
                             const float* __restrict__ emb_a,
                             const float* __restrict__ emb_b,
                             float* __restrict__ out,
                             int nnz, int split) {
    const int lane  = threadIdx.x & 63;
    const int wave  = (blockIdx.x * blockDim.x + threadIdx.x) >> 6;
    const int nwave = (gridDim.x * blockDim.x) >> 6;
    for (int e = wave; e < nnz; e += nwave) {
        const int   r = rows[e];
        const int   c = cols[e];
        const float v = vals[e];
        const float* xrow = (c < split) ? (emb_a + (size_t)c * DIM)
                                        : (emb_b + (size_t)(c - split) * DIM);
        unsafeAtomicAdd(out + (size_t)r * DIM + lane, v * xrow[lane]);
    }
}

extern "C" void kernel_launch(void* const* d_in, const int* in_sizes, int n_in,
                              void* d_out, int out_size, void* d_ws, size_t ws_size,
                              hipStream_t stream) {
    const float* user_emb  = (const float*)d_in[0];
    const float* item_emb  = (const float*)d_in[1];
    const int*   full_rows = (const int*)d_in[2];
    const int*   full_cols = (const int*)d_in[3];
    const float* full_vals = (const float*)d_in[4];
    const int*   user_rows = (const int*)d_in[5];
    const int*   user_cols = (const int*)d_in[6];
    const float* user_vals = (const float*)d_in[7];
    const int*   item_rows = (const int*)d_in[8];
    const int*   item_cols = (const int*)d_in[9];
    const float* item_vals = (const float*)d_in[10];

    float* out = (float*)d_out;

    const int nnz_full = in_sizes[2];
    const int nnz_user = in_sizes[5];
    const int nnz_item = in_sizes[8];
    const int nnz_tot  = nnz_full + nnz_user + nnz_item;

    // ws carve: bincnt | binoff | gcursor | rowptr | pad | pairs [| pairs2] [| tbl]
    size_t i_bincnt  = 0;
    size_t i_binoff  = i_bincnt + NBIN;
    size_t i_gcursor = i_binoff + NBIN + 1;
    size_t i_rowptr  = i_gcursor + NBIN;
    size_t i_end     = i_rowptr + NR_TOT + 1;
    i_end = (i_end + 3) & ~(size_t)3;
    size_t pairs_off   = i_end * sizeof(int);
    size_t pairs_bytes = (size_t)nnz_tot * sizeof(long long);
    size_t tbl_bytes   = (size_t)NR_X * DIM * sizeof(unsigned short);

    size_t after_pairs  = (pairs_off + pairs_bytes + 15) & ~(size_t)15;
    size_t pairs2_off   = after_pairs;
    size_t after_pairs2 = (pairs2_off + pairs_bytes + 15) & ~(size_t)15;

    size_t need_T3 = after_pairs2 + tbl_bytes;   // v2 sort + bf16
    size_t need_T2 = after_pairs + tbl_bytes;    // in-place sort + bf16
    size_t need_T1 = pairs_off + pairs_bytes;    // in-place sort + fp32

    if (ws_size < need_T1) {
        float* all1  = out;
        float* user2 = out + (size_t)NR_FULL * DIM;
        float* item2 = user2 + (size_t)NR_USER * DIM;
        hipMemsetAsync(d_out, 0, (size_t)out_size * sizeof(float), stream);
        spmm_scatter<<<4096, 256, 0, stream>>>(full_rows, full_cols, full_vals,
                                               user_emb, item_emb, all1, nnz_full, NUSR);
        spmm_scatter<<<4096, 256, 0, stream>>>(user_rows, user_cols, user_vals,
                                               user_emb, user_emb, user2, nnz_user, 0x7fffffff);
        spmm_scatter<<<4096, 256, 0, stream>>>(item_rows, item_cols, item_vals,
                                               item_emb, item_emb, item2, nnz_item, 0x7fffffff);
        return;
    }

    const bool v2_sort  = (ws_size >= need_T3);
    const bool use_bf16 = (ws_size >= need_T2);

    int*            ws_i    = (int*)d_ws;
    int*            bincnt  = ws_i + i_bincnt;
    int*            binoff  = ws_i + i_binoff;
    int*            gcursor = ws_i + i_gcursor;
    int*            rowptr  = ws_i + i_rowptr;
    long long*      pairs   = (long long*)((char*)d_ws + pairs_off);
    long long*      pairs2  = (long long*)((char*)d_ws + pairs2_off);
    unsigned short* tbl     = (unsigned short*)((char*)d_ws +
                                  (v2_sort ? after_pairs2 : after_pairs));

    hipMemsetAsync(bincnt, 0, NBIN * sizeof(int), stream);

    if (use_bf16)
        prep_kernel<<<1024, 256, 0, stream>>>(user_emb, item_emb, tbl,
                                              full_rows, nnz_full,
                                              user_rows, nnz_user,
                                              item_rows, nnz_item, bincnt);
    else
        hist_all<<<768, 256, 0, stream>>>(full_rows, nnz_full,
                                          user_rows, nnz_user,
                                          item_rows, nnz_item, bincnt);

    bin_scan<<<1, 1024, 0, stream>>>(bincnt, binoff, gcursor, nnz_tot);

    const int nchunk = (nnz_tot + PART_E - 1) / PART_E;
    partition_kernel<<<nchunk, PART_T, 0, stream>>>(
        full_rows, full_cols, full_vals, nnz_full,
        user_rows, user_cols, user_vals, nnz_user,
        item_rows, item_cols, item_vals, nnz_item,
        gcursor, pairs);

    const long long* sorted;
    if (v2_sort) {
        sort_bins_v2<<<NBIN, SORT_T, 0, stream>>>(binoff, pairs, pairs2,
                                                  rowptr, nnz_tot);
        sorted = pairs2;
    } else {
        sort_bins<<<NBIN, SORT_T, 0, stream>>>(binoff, pairs, rowptr, nnz_tot);
        sorted = pairs;
    }

    if (use_bf16)
        spmm_bf16<<<4096, 256, 0, stream>>>(rowptr, sorted, tbl, out);
    else
        spmm_rowreg<<<4096, 256, 0, stream>>>(rowptr, sorted, user_emb, item_emb, out);
}

// Round 14
// 264.277 us; speedup vs baseline: 1.0937x; 1.0937x over previous
//
#include <hip/hip_runtime.h>

#define NR_FULL 150000
#define NR_USER 100000
#define NR_ITEM 50000
#define NR_TOT  300000
#define NUSR    100000
#define NR_X    150000                 // unified x-table rows (user+item)
#define DIM     64

#define BIN_ROWS  512
#define BIN_SHIFT 9
#define NBIN ((NR_TOT + BIN_ROWS - 1) / BIN_ROWS)   // 586

#define PART_E 8192
#define PART_T 512

#define SORT_T    512
#define SORT_CAP  12288                // in-place variant: 96KB (full-bin mean 10240)
#define SORT2_CAP 5888                 // split variant: half-bin mean 5120 (+10 sigma)

typedef __attribute__((ext_vector_type(4))) float f32x4;

// ---------- 0) fused prep: bf16 table build + coarse bin histogram ----------
__device__ __forceinline__ unsigned short f2bf(float f) {
    unsigned b = __float_as_uint(f);
    return (unsigned short)((b + 0x7fffu + ((b >> 16) & 1u)) >> 16);   // RNE
}

__global__ void prep_kernel(const float* __restrict__ ue, const float* __restrict__ ie,
                            unsigned short* __restrict__ tbl,
                            const int* __restrict__ fr, int nf,
                            const int* __restrict__ ur, int nu,
                            const int* __restrict__ ir, int ni,
                            int* __restrict__ bincnt) {
    __shared__ int s_h[NBIN];
    for (int b = threadIdx.x; b < NBIN; b += blockDim.x) s_h[b] = 0;
    __syncthreads();

    int t = blockIdx.x * blockDim.x + threadIdx.x;
    int stride = gridDim.x * blockDim.x;

    // task A: bf16 table
    const int nq = NR_X * (DIM / 4);                     // 2.4M chunks
    for (int q = t; q < nq; q += stride) {
        int u  = q >> 4;
        int d4 = q & 15;
        const float* src = ((u < NUSR) ? ue + (size_t)u * DIM
                                       : ie + (size_t)(u - NUSR) * DIM) + d4 * 4;
        f32x4 f = *(const f32x4*)src;
        ushort4 h;
        h.x = f2bf(f.x); h.y = f2bf(f.y); h.z = f2bf(f.z); h.w = f2bf(f.w);
        ((ushort4*)tbl)[q] = h;
    }

    // task B: bin histogram (LDS pre-aggregated)
    int nvec = nf >> 2;
    for (int i = t; i < nvec; i += stride) {
        int4 r4 = ((const int4*)fr)[i];
        atomicAdd(&s_h[r4.x >> BIN_SHIFT], 1);
        atomicAdd(&s_h[r4.y >> BIN_SHIFT], 1);
        atomicAdd(&s_h[r4.z >> BIN_SHIFT], 1);
        atomicAdd(&s_h[r4.w >> BIN_SHIFT], 1);
    }
    for (int i = (nvec << 2) + t; i < nf; i += stride)
        atomicAdd(&s_h[fr[i] >> BIN_SHIFT], 1);

    nvec = nu >> 2;
    for (int i = t; i < nvec; i += stride) {
        int4 r4 = ((const int4*)ur)[i];
        atomicAdd(&s_h[(r4.x + NR_FULL) >> BIN_SHIFT], 1);
        atomicAdd(&s_h[(r4.y + NR_FULL) >> BIN_SHIFT], 1);
        atomicAdd(&s_h[(r4.z + NR_FULL) >> BIN_SHIFT], 1);
        atomicAdd(&s_h[(r4.w + NR_FULL) >> BIN_SHIFT], 1);
    }
    for (int i = (nvec << 2) + t; i < nu; i += stride)
        atomicAdd(&s_h[(ur[i] + NR_FULL) >> BIN_SHIFT], 1);

    nvec = ni >> 2;
    for (int i = t; i < nvec; i += stride) {
        int4 r4 = ((const int4*)ir)[i];
        atomicAdd(&s_h[(r4.x + NR_FULL + NR_USER) >> BIN_SHIFT], 1);
        atomicAdd(&s_h[(r4.y + NR_FULL + NR_USER) >> BIN_SHIFT], 1);
        atomicAdd(&s_h[(r4.z + NR_FULL + NR_USER) >> BIN_SHIFT], 1);
        atomicAdd(&s_h[(r4.w + NR_FULL + NR_USER) >> BIN_SHIFT], 1);
    }
    for (int i = (nvec << 2) + t; i < ni; i += stride)
        atomicAdd(&s_h[(ir[i] + NR_FULL + NR_USER) >> BIN_SHIFT], 1);

    __syncthreads();
    for (int b = threadIdx.x; b < NBIN; b += blockDim.x) {
        int c = s_h[b];
        if (c) atomicAdd(&bincnt[b], c);
    }
}

// ---------- 1-alt) hist only (fp32 fallback tier) ----------
__global__ void hist_all(const int* __restrict__ fr, int nf,
                         const int* __restrict__ ur, int nu,
                         const int* __restrict__ ir, int ni,
                         int* __restrict__ bincnt) {
    __shared__ int s_h[NBIN];
    for (int b = threadIdx.x; b < NBIN; b += blockDim.x) s_h[b] = 0;
    __syncthreads();
    int t = blockIdx.x * blockDim.x + threadIdx.x;
    int stride = gridDim.x * blockDim.x;
    int nvec = nf >> 2;
    for (int i = t; i < nvec; i += stride) {
        int4 r4 = ((const int4*)fr)[i];
        atomicAdd(&s_h[r4.x >> BIN_SHIFT], 1);
        atomicAdd(&s_h[r4.y >> BIN_SHIFT], 1);
        atomicAdd(&s_h[r4.z >> BIN_SHIFT], 1);
        atomicAdd(&s_h[r4.w >> BIN_SHIFT], 1);
    }
    for (int i = (nvec << 2) + t; i < nf; i += stride)
        atomicAdd(&s_h[fr[i] >> BIN_SHIFT], 1);
    nvec = nu >> 2;
    for (int i = t; i < nvec; i += stride) {
        int4 r4 = ((const int4*)ur)[i];
        atomicAdd(&s_h[(r4.x + NR_FULL) >> BIN_SHIFT], 1);
        atomicAdd(&s_h[(r4.y + NR_FULL) >> BIN_SHIFT], 1);
        atomicAdd(&s_h[(r4.z + NR_FULL) >> BIN_SHIFT], 1);
        atomicAdd(&s_h[(r4.w + NR_FULL) >> BIN_SHIFT], 1);
    }
    for (int i = (nvec << 2) + t; i < nu; i += stride)
        atomicAdd(&s_h[(ur[i] + NR_FULL) >> BIN_SHIFT], 1);
    nvec = ni >> 2;
    for (int i = t; i < nvec; i += stride) {
        int4 r4 = ((const int4*)ir)[i];
        atomicAdd(&s_h[(r4.x + NR_FULL + NR_USER) >> BIN_SHIFT], 1);
        atomicAdd(&s_h[(r4.y + NR_FULL + NR_USER) >> BIN_SHIFT], 1);
        atomicAdd(&s_h[(r4.z + NR_FULL + NR_USER) >> BIN_SHIFT], 1);
        atomicAdd(&s_h[(r4.w + NR_FULL + NR_USER) >> BIN_SHIFT], 1);
    }
    for (int i = (nvec << 2) + t; i < ni; i += stride)
        atomicAdd(&s_h[(ir[i] + NR_FULL + NR_USER) >> BIN_SHIFT], 1);
    __syncthreads();
    for (int b = threadIdx.x; b < NBIN; b += blockDim.x) {
        int c = s_h[b];
        if (c) atomicAdd(&bincnt[b], c);
    }
}

// ---------- 2) scan bins -> binoff (NBIN+1) + gcursor ----------
__global__ void bin_scan(const int* __restrict__ bincnt, int* __restrict__ binoff,
                         int* __restrict__ gcursor, int nnz_tot) {
    __shared__ int s[NBIN];
    int t = threadIdx.x;
    if (t < NBIN) s[t] = bincnt[t];
    __syncthreads();
    for (int off = 1; off < NBIN; off <<= 1) {
        int a = 0;
        if (t < NBIN && t >= off) a = s[t - off];
        __syncthreads();
        if (t < NBIN) s[t] += a;
        __syncthreads();
    }
    if (t < NBIN) {
        int excl = (t == 0) ? 0 : s[t - 1];
        binoff[t] = excl;
        gcursor[t] = excl;
    }
    if (t == 0) binoff[NBIN] = nnz_tot;
}

// ---------- 3) block-local counting sort -> bin-grouped pairs ----------
// pair: low32 = val bits; high32 = (rlocal<<18) | ucol (unified x index)
__global__ __launch_bounds__(PART_T) void partition_kernel(
    const int* __restrict__ fr, const int* __restrict__ fc, const float* __restrict__ fv, int nf,
    const int* __restrict__ ur, const int* __restrict__ uc, const float* __restrict__ uv, int nu,
    const int* __restrict__ ir, const int* __restrict__ ic, const float* __restrict__ iv, int ni,
    int* __restrict__ gcursor, long long* __restrict__ pairs) {
    __shared__ long long s_stage[PART_E];        // 64 KB
    __shared__ int s_cnt[NBIN];
    __shared__ int s_start[NBIN + 1];
    __shared__ int s_cur[NBIN];
    __shared__ int s_gbase[NBIN];

    const int t = threadIdx.x;
    const int ntot = nf + nu + ni;
    const int base = blockIdx.x * PART_E;
    const int nE = min(PART_E, ntot - base);

    for (int b = t; b < NBIN; b += PART_T) s_cnt[b] = 0;
    __syncthreads();

    for (int k = 0; k < PART_E / PART_T; ++k) {
        int j = k * PART_T + t;
        if (j < nE) {
            int i = base + j;
            int g;
            if (i < nf)            g = fr[i];
            else if (i < nf + nu)  g = ur[i - nf] + NR_FULL;
            else                   g = ir[i - nf - nu] + NR_FULL + NR_USER;
            atomicAdd(&s_cnt[g >> BIN_SHIFT], 1);
        }
    }
    __syncthreads();

    for (int off = 1; off < NBIN; off <<= 1) {
        int i0 = t, i1 = t + PART_T;
        int a0 = (i0 < NBIN && i0 >= off) ? s_cnt[i0 - off] : 0;
        int a1 = (i1 < NBIN && i1 >= off) ? s_cnt[i1 - off] : 0;
        __syncthreads();
        if (i0 < NBIN) s_cnt[i0] += a0;
        if (i1 < NBIN) s_cnt[i1] += a1;
        __syncthreads();
    }
    for (int b = t; b < NBIN; b += PART_T) {
        int st = (b == 0) ? 0 : s_cnt[b - 1];
        s_start[b] = st;
        s_cur[b]   = st;
    }
    if (t == 0) s_start[NBIN] = s_cnt[NBIN - 1];
    __syncthreads();

    for (int b = t; b < NBIN; b += PART_T) {
        int cnt = s_start[b + 1] - s_start[b];
        s_gbase[b] = cnt ? atomicAdd(&gcursor[b], cnt) : 0;
    }

    for (int k = 0; k < PART_E / PART_T; ++k) {
        int j = k * PART_T + t;
        if (j < nE) {
            int i = base + j;
            int g, u; float v;
            if (i < nf)           { g = fr[i];                          u = fc[i];        v = fv[i]; }
            else if (i < nf + nu) { int q = i - nf;      g = ur[q] + NR_FULL;            u = uc[q];        v = uv[q]; }
            else                  { int q = i - nf - nu; g = ir[q] + NR_FULL + NR_USER;  u = ic[q] + NUSR; v = iv[q]; }
            int bin = g >> BIN_SHIFT;
            int rl  = g & (BIN_ROWS - 1);
            int lpos = atomicAdd(&s_cur[bin], 1);
            unsigned hi = ((unsigned)rl << 18) | (unsigned)u;
            s_stage[lpos] = ((long long)hi << 32) | (long long)__float_as_uint(v);
        }
    }
    __syncthreads();

    for (int j = t; j < nE; j += PART_T) {
        int lo = 0, hi2 = NBIN;
        while (hi2 - lo > 1) {
            int mid = (lo + hi2) >> 1;
            if (s_start[mid] <= j) lo = mid; else hi2 = mid;
        }
        pairs[s_gbase[lo] + (j - s_start[lo])] = s_stage[j];
    }
}

// ---------- 3b-split) within-bin row sort, 2 blocks/bin, out-of-place ----------
__global__ __launch_bounds__(SORT_T) void sort_bins_split(
    const int* __restrict__ binoff, const long long* __restrict__ pairs,
    long long* __restrict__ pairs2, int* __restrict__ rowptr, int nnz_tot) {
    __shared__ long long s_stage[SORT2_CAP];     // 46 KB
    __shared__ int s_cnt[BIN_ROWS];
    __shared__ int s_start[BIN_ROWS];
    __shared__ int s_cur[BIN_ROWS];

    const int t    = threadIdx.x;
    const int bin  = blockIdx.x >> 1;
    const int half = blockIdx.x & 1;
    const int r0   = half * (BIN_ROWS / 2);
    const int r1   = r0 + (BIN_ROWS / 2);
    const int beg  = binoff[bin], end = binoff[bin + 1];
    const int nE   = end - beg;

    s_cnt[t] = 0;
    __syncthreads();

    const unsigned* hi32 = (const unsigned*)(pairs + beg) + 1;   // stride 2
    for (int j = t; j < nE; j += SORT_T)
        atomicAdd(&s_cnt[hi32[2 * j] >> 18], 1);
    __syncthreads();

    for (int off = 1; off < BIN_ROWS; off <<= 1) {
        int a = (t >= off) ? s_cnt[t - off] : 0;
        __syncthreads();
        s_cnt[t] += a;
        __syncthreads();
    }
    int excl = (t == 0) ? 0 : s_cnt[t - 1];
    s_start[t] = excl;
    s_cur[t]   = excl;
    if (t >= r0 && t < r1) {
        int g = bin * BIN_ROWS + t;
        if (g < NR_TOT) rowptr[g] = beg + excl;
    }
    if (bin == 0 && half == 0 && t == 0) rowptr[NR_TOT] = nnz_tot;
    __syncthreads();

    const int myBase  = s_start[r0];
    const int myCount = ((r1 < BIN_ROWS) ? s_start[r1] : s_cnt[BIN_ROWS - 1]) - myBase;
    const int nS = myCount < SORT2_CAP ? myCount : SORT2_CAP;

    for (int j = t; j < nE; j += SORT_T) {
        long long pe = pairs[beg + j];
        int rl = (int)((unsigned)((unsigned long long)pe >> 32) >> 18);
        if (rl >= r0 && rl < r1) {
            int pos = atomicAdd(&s_cur[rl], 1) - myBase;
            if (pos < SORT2_CAP) s_stage[pos] = pe;
        }
    }
    __syncthreads();

    for (int j = t; j < nS; j += SORT_T)
        pairs2[beg + myBase + j] = s_stage[j];
}

// ---------- 3b-inplace) fallback when ws lacks pairs2 ----------
__global__ __launch_bounds__(SORT_T) void sort_bins(
    const int* __restrict__ binoff, long long* __restrict__ pairs,
    int* __restrict__ rowptr, int nnz_tot) {
    __shared__ long long s_stage[SORT_CAP];      // 96 KB
    __shared__ int s_cnt[BIN_ROWS];
    __shared__ int s_start[BIN_ROWS];
    __shared__ int s_cur[BIN_ROWS];

    const int t   = threadIdx.x;
    const int bin = blockIdx.x;
    const int beg = binoff[bin], end = binoff[bin + 1];
    const int nE  = end - beg;
    const int nS  = nE < SORT_CAP ? nE : SORT_CAP;

    s_cnt[t] = 0;
    __syncthreads();
    for (int j = t; j < nE; j += SORT_T) {
        unsigned hi = (unsigned)((unsigned long long)pairs[beg + j] >> 32);
        atomicAdd(&s_cnt[hi >> 18], 1);
    }
    __syncthreads();
    for (int off = 1; off < BIN_ROWS; off <<= 1) {
        int a = (t >= off) ? s_cnt[t - off] : 0;
        __syncthreads();
        s_cnt[t] += a;
        __syncthreads();
    }
    int excl = (t == 0) ? 0 : s_cnt[t - 1];
    s_start[t] = excl;
    s_cur[t]   = excl;
    int g = bin * BIN_ROWS + t;
    if (g < NR_TOT) rowptr[g] = beg + excl;
    if (bin == 0 && t == 0) rowptr[NR_TOT] = nnz_tot;
    __syncthreads();
    for (int j = t; j < nE; j += SORT_T) {
        long long pe = pairs[beg + j];
        unsigned hi = (unsigned)((unsigned long long)pe >> 32);
        int pos = atomicAdd(&s_cur[hi >> 18], 1);
        if (pos < SORT_CAP) s_stage[pos] = pe;
    }
    __syncthreads();
    for (int j = t; j < nS; j += SORT_T)
        pairs[beg + j] = s_stage[j];
}

// ---------- 4) SpMM (bf16 gathers): one wave per row, 8x8 structure ----------
// 8 x 8-lane groups; lane loads 16B (8 lanes = 128B row); group owns 2
// contiguous edges -> 16 edges in flight per wave-iter, 4 VMEM instr/iter
// (proven 125us; 16-lane/8B form was 168us, unroll-8 variant 187us).
__global__ void spmm_bf16(const int* __restrict__ rowptr,
                          const long long* __restrict__ pairs,
                          const unsigned short* __restrict__ tbl,
                          float* __restrict__ out) {
    const int lane = threadIdx.x & 63;
    const int sub  = lane & 7;           // 16B slot within 128B bf16 row
    const int grp  = lane >> 3;          // edge group 0..7
    int wave  = (blockIdx.x * blockDim.x + threadIdx.x) >> 6;
    int nwave = (gridDim.x * blockDim.x) >> 6;
    for (int g = wave; g < NR_TOT; g += nwave) {
        int beg = rowptr[g], end = rowptr[g + 1];
        float acc[8] = {0.f, 0.f, 0.f, 0.f, 0.f, 0.f, 0.f, 0.f};
        if (beg < end) {
            int elast = end - 1;
            for (int e0 = beg + grp * 2; e0 < end; e0 += 16) {
                float v[2];
                uint4 h[2];
#pragma unroll
                for (int i = 0; i < 2; ++i) {
                    int ee = e0 + i;
                    bool ok = ee < end;
                    ee = ok ? ee : elast;
                    long long p = __builtin_nontemporal_load(&pairs[ee]);
                    v[i] = ok ? __uint_as_float((unsigned)p) : 0.f;
                    unsigned u = ((unsigned)((unsigned long long)p >> 32)) & 0x3FFFF;
                    h[i] = ((const uint4*)(tbl + (size_t)u * DIM))[sub];
                }
#pragma unroll
                for (int i = 0; i < 2; ++i) {
                    acc[0] = fmaf(v[i], __uint_as_float(h[i].x << 16),         acc[0]);
                    acc[1] = fmaf(v[i], __uint_as_float(h[i].x & 0xffff0000u), acc[1]);
                    acc[2] = fmaf(v[i], __uint_as_float(h[i].y << 16),         acc[2]);
                    acc[3] = fmaf(v[i], __uint_as_float(h[i].y & 0xffff0000u), acc[3]);
                    acc[4] = fmaf(v[i], __uint_as_float(h[i].z << 16),         acc[4]);
                    acc[5] = fmaf(v[i], __uint_as_float(h[i].z & 0xffff0000u), acc[5]);
                    acc[6] = fmaf(v[i], __uint_as_float(h[i].w << 16),         acc[6]);
                    acc[7] = fmaf(v[i], __uint_as_float(h[i].w & 0xffff0000u), acc[7]);
                }
            }
#pragma unroll
            for (int k = 0; k < 8; ++k) {
                acc[k] += __shfl_xor(acc[k], 8);
                acc[k] += __shfl_xor(acc[k], 16);
                acc[k] += __shfl_xor(acc[k], 32);
            }
        }
        if (grp == 0) {
            f32x4 lo = {acc[0], acc[1], acc[2], acc[3]};
            f32x4 hi = {acc[4], acc[5], acc[6], acc[7]};
            f32x4* o = (f32x4*)(out + (size_t)g * DIM) + sub * 2;
            __builtin_nontemporal_store(lo, o);
            __builtin_nontemporal_store(hi, o + 1);
        }
    }
}

// ---------- 4-alt) fp32 rowreg SpMM (used if ws lacks bf16 table) ----------
__global__ void spmm_rowreg(const int* __restrict__ rowptr,
                            const long long* __restrict__ pairs,
                            const float* __restrict__ user_emb,
                            const float* __restrict__ item_emb,
                            float* __restrict__ out) {
    const int lane = threadIdx.x & 63;
    const int sub  = lane & 15;
    const int grp  = lane >> 4;
    int wave  = (blockIdx.x * blockDim.x + threadIdx.x) >> 6;
    int nwave = (gridDim.x * blockDim.x) >> 6;
    for (int g = wave; g < NR_TOT; g += nwave) {
        int beg = rowptr[g], end = rowptr[g + 1];
        f32x4 acc = {0.f, 0.f, 0.f, 0.f};
        if (beg < end) {
            int elast = end - 1;
            for (int e = beg + grp; e < end; e += 8) {
                long long p0 = __builtin_nontemporal_load(&pairs[e]);
                int e1 = e + 4; bool ok1 = e1 <= elast; e1 = ok1 ? e1 : elast;
                long long p1 = __builtin_nontemporal_load(&pairs[e1]);
                float v0 = __uint_as_float((unsigned)p0);
                float v1 = ok1 ? __uint_as_float((unsigned)p1) : 0.f;
                unsigned u0 = ((unsigned)((unsigned long long)p0 >> 32)) & 0x3FFFF;
                unsigned u1 = ((unsigned)((unsigned long long)p1 >> 32)) & 0x3FFFF;
                const float* x0 = (u0 < NUSR) ? user_emb + (size_t)u0 * DIM
                                              : item_emb + (size_t)(u0 - NUSR) * DIM;
                const float* x1 = (u1 < NUSR) ? user_emb + (size_t)u1 * DIM
                                              : item_emb + (size_t)(u1 - NUSR) * DIM;
                f32x4 a = ((const f32x4*)x0)[sub];
                f32x4 b = ((const f32x4*)x1)[sub];
                acc.x = fmaf(v0, a.x, acc.x); acc.y = fmaf(v0, a.y, acc.y);
                acc.z = fmaf(v0, a.z, acc.z); acc.w = fmaf(v0, a.w, acc.w);
                acc.x = fmaf(v1, b.x, acc.x); acc.y = fmaf(v1, b.y, acc.y);
                acc.z = fmaf(v1, b.z, acc.z); acc.w = fmaf(v1, b.w, acc.w);
            }
            acc.x += __shfl_xor(acc.x, 16); acc.y += __shfl_xor(acc.y, 16);
            acc.z += __shfl_xor(acc.z, 16); acc.w += __shfl_xor(acc.w, 16);
            acc.x += __shfl_xor(acc.x, 32); acc.y += __shfl_xor(acc.y, 32);
            acc.z += __shfl_xor(acc.z, 32); acc.w += __shfl_xor(acc.w, 32);
        }
        if (grp == 0)
            __builtin_nontemporal_store(acc, (f32x4*)(out + (size_t)g * DIM) + sub);
    }
}

// ---------------- last-resort fallback (round-1 atomic scatter) ----------------
__global__ void spmm_scatter(const int* __restrict__ rows,
                             const int* __restrict__ cols,
                             const float* __restrict__ vals,
                             const float* __restrict__ emb_a,
                             const float* __restrict__ emb_b,
                             float* __restrict__ out,
                             int nnz, int split) {
    const int lane  = threadIdx.x & 63;
    const int wave  = (blockIdx.x * blockDim.x + threadIdx.x) >> 6;
    const int nwave = (gridDim.x * blockDim.x) >> 6;
    for (int e = wave; e < nnz; e += nwave) {
        const int   r = rows[e];
        const int   c = cols[e];
        const float v = vals[e];
        const float* xrow = (c < split) ? (emb_a + (size_t)c * DIM)
                                        : (emb_b + (size_t)(c - split) * DIM);
        unsafeAtomicAdd(out + (size_t)r * DIM + lane, v * xrow[lane]);
    }
}

extern "C" void kernel_launch(void* const* d_in, const int* in_sizes, int n_in,
                              void* d_out, int out_size, void* d_ws, size_t ws_size,
                              hipStream_t stream) {
    const float* user_emb  = (const float*)d_in[0];
    const float* item_emb  = (const float*)d_in[1];
    const int*   full_rows = (const int*)d_in[2];
    const int*   full_cols = (const int*)d_in[3];
    const float* full_vals = (const float*)d_in[4];
    const int*   user_rows = (const int*)d_in[5];
    const int*   user_cols = (const int*)d_in[6];
    const float* user_vals = (const float*)d_in[7];
    const int*   item_rows = (const int*)d_in[8];
    const int*   item_cols = (const int*)d_in[9];
    const float* item_vals = (const float*)d_in[10];

    float* out = (float*)d_out;

    const int nnz_full = in_sizes[2];
    const int nnz_user = in_sizes[5];
    const int nnz_item = in_sizes[8];
    const int nnz_tot  = nnz_full + nnz_user + nnz_item;

    // ws carve: bincnt | binoff | gcursor | rowptr | pad | pairs [| pairs2] [| tbl]
    size_t i_bincnt  = 0;
    size_t i_binoff  = i_bincnt + NBIN;
    size_t i_gcursor = i_binoff + NBIN + 1;
    size_t i_rowptr  = i_gcursor + NBIN;
    size_t i_end     = i_rowptr + NR_TOT + 1;
    i_end = (i_end + 3) & ~(size_t)3;
    size_t pairs_off   = i_end * sizeof(int);
    size_t pairs_bytes = (size_t)nnz_tot * sizeof(long long);
    size_t tbl_bytes   = (size_t)NR_X * DIM * sizeof(unsigned short);

    size_t after_pairs  = (pairs_off + pairs_bytes + 15) & ~(size_t)15;
    size_t pairs2_off   = after_pairs;
    size_t after_pairs2 = (pairs2_off + pairs_bytes + 15) & ~(size_t)15;

    size_t need_T3 = after_pairs2 + tbl_bytes;   // split sort + bf16
    size_t need_T2 = after_pairs + tbl_bytes;    // in-place sort + bf16
    size_t need_T1 = pairs_off + pairs_bytes;    // in-place sort + fp32

    if (ws_size < need_T1) {
        float* all1  = out;
        float* user2 = out + (size_t)NR_FULL * DIM;
        float* item2 = user2 + (size_t)NR_USER * DIM;
        hipMemsetAsync(d_out, 0, (size_t)out_size * sizeof(float), stream);
        spmm_scatter<<<4096, 256, 0, stream>>>(full_rows, full_cols, full_vals,
                                               user_emb, item_emb, all1, nnz_full, NUSR);
        spmm_scatter<<<4096, 256, 0, stream>>>(user_rows, user_cols, user_vals,
                                               user_emb, user_emb, user2, nnz_user, 0x7fffffff);
        spmm_scatter<<<4096, 256, 0, stream>>>(item_rows, item_cols, item_vals,
                                               item_emb, item_emb, item2, nnz_item, 0x7fffffff);
        return;
    }

    const bool split_sort = (ws_size >= need_T3);
    const bool use_bf16   = (ws_size >= need_T2);

    int*            ws_i    = (int*)d_ws;
    int*            bincnt  = ws_i + i_bincnt;
    int*            binoff  = ws_i + i_binoff;
    int*            gcursor = ws_i + i_gcursor;
    int*            rowptr  = ws_i + i_rowptr;
    long long*      pairs   = (long long*)((char*)d_ws + pairs_off);
    long long*      pairs2  = (long long*)((char*)d_ws + pairs2_off);
    unsigned short* tbl     = (unsigned short*)((char*)d_ws +
                                  (split_sort ? after_pairs2 : after_pairs));

    hipMemsetAsync(bincnt, 0, NBIN * sizeof(int), stream);

    if (use_bf16)
        prep_kernel<<<1024, 256, 0, stream>>>(user_emb, item_emb, tbl,
                                              full_rows, nnz_full,
                                              user_rows, nnz_user,
                                              item_rows, nnz_item, bincnt);
    else
        hist_all<<<768, 256, 0, stream>>>(full_rows, nnz_full,
                                          user_rows, nnz_user,
                                          item_rows, nnz_item, bincnt);

    bin_scan<<<1, 1024, 0, stream>>>(bincnt, binoff, gcursor, nnz_tot);

    const int nchunk = (nnz_tot + PART_E - 1) / PART_E;
    partition_kernel<<<nchunk, PART_T, 0, stream>>>(
        full_rows, full_cols, full_vals, nnz_full,
        user_rows, user_cols, user_vals, nnz_user,
        item_rows, item_cols, item_vals, nnz_item,
        gcursor, pairs);

    const long long* sorted;
    if (split_sort) {
        sort_bins_split<<<NBIN * 2, SORT_T, 0, stream>>>(binoff, pairs, pairs2,
                                                         rowptr, nnz_tot);
        sorted = pairs2;
    } else {
        sort_bins<<<NBIN, SORT_T, 0, stream>>>(binoff, pairs, rowptr, nnz_tot);
        sorted = pairs;
    }

    if (use_bf16)
        spmm_bf16<<<4096, 256, 0, stream>>>(rowptr, sorted, tbl, out);
    else
        spmm_rowreg<<<4096, 256, 0, stream>>>(rowptr, sorted, user_emb, item_emb, out);
}